// Round 1
// baseline (496.298 us; speedup 1.0000x reference)
//
#include <hip/hip_runtime.h>

// Problem constants (match the reference).
#define NB 128
#define HH 512
#define WW 512
#define HW (HH * WW)

constexpr float EPS_F = 1e-6f;
constexpr int IGNORE_V = -255;

constexpr int TPB = 256;               // threads per block
constexpr int G = 4;                   // float4 per prefetch group (sum/fill kernel)
constexpr int NG = 4;                  // groups per thread (sum/fill kernel)
constexpr int F4T = G * NG;            // 16 float4 per thread
constexpr int EPB = TPB * F4T * 4;     // 16384 elements per block
constexpr int BPR = HW / EPB;          // 16 blocks per row (grid 16x128 = 2048 = 8/CU)

// Score kernel pipelining: 3 streams, shallower groups to keep VGPR in check.
constexpr int G2 = 2;                  // float4 per prefetch group per stream
constexpr int NG2 = 8;                 // groups per thread (G2*NG2*4*TPB == EPB)

// Native Clang vector types — accepted by __builtin_nontemporal_load/store.
typedef float floatx4 __attribute__((ext_vector_type(4)));
typedef int intx4 __attribute__((ext_vector_type(4)));

// Monotone packing: larger float => larger key; equal float => lower index wins
// (matches top_k first-occurrence tie-break). Inputs here are >= 0 finite.
__device__ inline unsigned long long pack_key(float f, unsigned idx) {
    unsigned bits = __float_as_uint(f);
    bits ^= (bits & 0x80000000u) ? 0xFFFFFFFFu : 0x80000000u;
    return ((unsigned long long)bits << 32) | (unsigned)(~idx);
}

// ---------------------------------------------------------------------------
// Pass 1: copy-shaped. Read cam (plain loads -> L2/L3 stay hot for pass 2),
// nt-store the IGNORE fill, per-block partial sums of (cam+eps).
// Element/summation order is IDENTICAL to the previous passing kernel.
// ---------------------------------------------------------------------------
__global__ __launch_bounds__(TPB, 4) void k_sum_fill(const float* __restrict__ cam,
                                                     int* __restrict__ out,
                                                     float* __restrict__ partial) {
    const int b = blockIdx.y, chunk = blockIdx.x, t = threadIdx.x;
    const long base = (long)b * HW + (long)chunk * EPB;
    const floatx4* c4 = (const floatx4*)(cam + base);
    intx4* o4 = (intx4*)(out + base);
    const intx4 fill = {IGNORE_V, IGNORE_V, IGNORE_V, IGNORE_V};

    floatx4 cb[2][G];
#pragma unroll
    for (int k = 0; k < G; ++k) cb[0][k] = c4[t + k * TPB];

    float s = 0.f;
#pragma unroll
    for (int g = 0; g < NG; ++g) {
        const int cur = g & 1, nxt = cur ^ 1;
        if (g + 1 < NG) {
#pragma unroll
            for (int k = 0; k < G; ++k) cb[nxt][k] = c4[t + ((g + 1) * G + k) * TPB];
        }
#pragma unroll
        for (int k = 0; k < G; ++k) {
            const int slot = g * G + k;
            __builtin_nontemporal_store(fill, &o4[t + slot * TPB]);
            floatx4 v = cb[cur][k];
#pragma unroll
            for (int j = 0; j < 4; ++j) {
                float a = v[j] + EPS_F;
                s += a;
            }
        }
    }

    // wave64 reduction -> per-block partial (deterministic, no atomics)
#pragma unroll
    for (int off = 32; off > 0; off >>= 1) s += __shfl_down(s, off, 64);
    __shared__ float ls[TPB / 64];
    if ((t & 63) == 0) ls[t >> 6] = s;
    __syncthreads();
    if (t == 0) {
        float tot = 0.f;
#pragma unroll
        for (int w = 0; w < TPB / 64; ++w) tot += ls[w];
        partial[b * BPR + chunk] = tot;
    }
}

// ---------------------------------------------------------------------------
// Pass 2: fused FG + BG scoring in one sweep.
// FG key:  (cam+eps)/(-log u_fg)        (S cancels in argmax log p + g)
// BG key:  (S-(cam+eps))/(-log u_bg)    (S from pass-1 partials)
// cam re-read hits L3 (kept resident by plain loads in pass 1); noise arrays
// are read-once -> nt loads. No bulk stores here.
// ---------------------------------------------------------------------------
__global__ __launch_bounds__(TPB, 4) void k_score(const float* __restrict__ cam,
                                                  const float* __restrict__ ufg,
                                                  const float* __restrict__ ubg,
                                                  const float* __restrict__ partial,
                                                  unsigned long long* __restrict__ bestFg,
                                                  unsigned long long* __restrict__ bestBg) {
    const int b = blockIdx.y, chunk = blockIdx.x, t = threadIdx.x;

    float S = 0.f;
    for (int i = 0; i < BPR; ++i) S += partial[b * BPR + i];

    const long base = (long)b * HW + (long)chunk * EPB;
    const floatx4* c4 = (const floatx4*)(cam + base);
    const floatx4* f4 = (const floatx4*)(ufg + base);
    const floatx4* g4 = (const floatx4*)(ubg + base);

    floatx4 cb[2][G2], fb[2][G2], gb[2][G2];
#pragma unroll
    for (int k = 0; k < G2; ++k) {
        cb[0][k] = c4[t + k * TPB];
        fb[0][k] = __builtin_nontemporal_load(&f4[t + k * TPB]);
        gb[0][k] = __builtin_nontemporal_load(&g4[t + k * TPB]);
    }

    unsigned long long bf = 0ull, bb = 0ull;
#pragma unroll
    for (int g = 0; g < NG2; ++g) {
        const int cur = g & 1, nxt = cur ^ 1;
        if (g + 1 < NG2) {
#pragma unroll
            for (int k = 0; k < G2; ++k) {
                cb[nxt][k] = c4[t + ((g + 1) * G2 + k) * TPB];
                fb[nxt][k] = __builtin_nontemporal_load(&f4[t + ((g + 1) * G2 + k) * TPB]);
                gb[nxt][k] = __builtin_nontemporal_load(&g4[t + ((g + 1) * G2 + k) * TPB]);
            }
        }
#pragma unroll
        for (int k = 0; k < G2; ++k) {
            const int slot = g * G2 + k;
            floatx4 v = cb[cur][k];
            floatx4 uf = fb[cur][k];
            floatx4 ug = gb[cur][k];
            const unsigned idx0 = (unsigned)chunk * (unsigned)EPB + (unsigned)(t + slot * TPB) * 4u;
#pragma unroll
            for (int j = 0; j < 4; ++j) {
                float a = v[j] + EPS_F;
                float Ef = -logf(fmaxf(uf[j], 1e-12f));      // -log(u) > 0
                unsigned long long kf = pack_key(a / Ef, idx0 + j);
                bf = kf > bf ? kf : bf;
                float Eb = -logf(fmaxf(ug[j], 1e-12f));
                unsigned long long kb = pack_key((S - a) / Eb, idx0 + j);
                bb = kb > bb ? kb : bb;
            }
        }
    }

    // dual wave64 max reductions -> per-block outputs
#pragma unroll
    for (int off = 32; off > 0; off >>= 1) {
        unsigned long long of = __shfl_down(bf, off, 64);
        bf = of > bf ? of : bf;
        unsigned long long ob = __shfl_down(bb, off, 64);
        bb = ob > bb ? ob : bb;
    }
    __shared__ unsigned long long lf[TPB / 64];
    __shared__ unsigned long long lb[TPB / 64];
    if ((t & 63) == 0) { lf[t >> 6] = bf; lb[t >> 6] = bb; }
    __syncthreads();
    if (t == 0) {
#pragma unroll
        for (int w = 1; w < TPB / 64; ++w) {
            if (lf[w] > bf) bf = lf[w];
            if (lb[w] > bb) bb = lb[w];
        }
        bestFg[b * BPR + chunk] = bf;
        bestBg[b * BPR + chunk] = bb;
    }
}

// ---------------------------------------------------------------------------
// Pass 3: final per-row max over BPR candidates, then write the dilated 3x3
// blocks with the overlap rule: fg\bg -> 1, bg\fg -> 0, overlap stays IGNORE.
// ---------------------------------------------------------------------------
__global__ void k_fixup(const unsigned long long* __restrict__ bestFg,
                        const unsigned long long* __restrict__ bestBg,
                        int* __restrict__ out) {
    const int b = threadIdx.x;
    if (b >= NB) return;
    unsigned long long bf = 0ull, bb = 0ull;
    for (int i = 0; i < BPR; ++i) {
        unsigned long long f = bestFg[b * BPR + i];
        unsigned long long g = bestBg[b * BPR + i];
        if (f > bf) bf = f;
        if (g > bb) bb = g;
    }
    const unsigned fidx = ~(unsigned)(bf & 0xFFFFFFFFull);
    const unsigned bidx = ~(unsigned)(bb & 0xFFFFFFFFull);
    const int fr = (int)(fidx / WW), fc = (int)(fidx % WW);
    const int br = (int)(bidx / WW), bc = (int)(bidx % WW);
    const long rb = (long)b * HW;

    for (int dr = -1; dr <= 1; ++dr) {
        for (int dc = -1; dc <= 1; ++dc) {
            int r = fr + dr, c = fc + dc;
            if (r >= 0 && r < HH && c >= 0 && c < WW) {
                bool inBg = (r >= br - 1 && r <= br + 1 && c >= bc - 1 && c <= bc + 1);
                if (!inBg) out[rb + (long)r * WW + c] = 1;
            }
            r = br + dr; c = bc + dc;
            if (r >= 0 && r < HH && c >= 0 && c < WW) {
                bool inFg = (r >= fr - 1 && r <= fr + 1 && c >= fc - 1 && c <= fc + 1);
                if (!inFg) out[rb + (long)r * WW + c] = 0;
            }
        }
    }
}

extern "C" void kernel_launch(void* const* d_in, const int* in_sizes, int n_in,
                              void* d_out, int out_size, void* d_ws, size_t ws_size,
                              hipStream_t stream) {
    const float* cam = (const float*)d_in[0];   // x: [128,1,512,512] f32
    const float* ufg = (const float*)d_in[1];   // u_fg: [128, HW] f32
    const float* ubg = (const float*)d_in[2];   // u_bg: [128, HW] f32
    int* out = (int*)d_out;                     // int32 [128,512,512]

    // Workspace layout (fully written before read; no init needed):
    //   [0,     8192)  float  partial[NB*BPR]          (128*16*4 = 8 KB)
    //   [8192, 24576)  ull    bestFg[NB*BPR]           (16 KB)
    //   [24576,40960)  ull    bestBg[NB*BPR]           (16 KB)
    float* partial = (float*)d_ws;
    unsigned long long* bestFg = (unsigned long long*)((char*)d_ws + 8192);
    unsigned long long* bestBg = (unsigned long long*)((char*)d_ws + 24576);

    dim3 grid(BPR, NB);
    k_sum_fill<<<grid, TPB, 0, stream>>>(cam, out, partial);
    k_score<<<grid, TPB, 0, stream>>>(cam, ufg, ubg, partial, bestFg, bestBg);
    k_fixup<<<1, 128, 0, stream>>>(bestFg, bestBg, out);
}

// Round 2
// 405.997 us; speedup vs baseline: 1.2224x; 1.2224x over previous
//
#include <hip/hip_runtime.h>

// Problem constants (match the reference).
#define NB 128
#define HH 512
#define WW 512
#define HW (HH * WW)

constexpr float EPS_F = 1e-6f;
constexpr int IGNORE_V = -255;

constexpr int TPB = 256;               // threads per block
constexpr int VPT = 4;                 // float4 per thread per stream
constexpr int EPB = TPB * VPT * 4;     // 4096 elements per block
constexpr int BPR = HW / EPB;          // 64 blocks per row -> grid 64x128 = 8192 blocks

// Native Clang vector types — accepted by __builtin_nontemporal_load/store.
typedef float floatx4 __attribute__((ext_vector_type(4)));
typedef int intx4 __attribute__((ext_vector_type(4)));

// Monotone packing for POSITIVE finite floats: larger float => larger key;
// equal float => lower index wins (matches top_k first-occurrence tie-break).
// All keys here are > 0 (cam+eps > 0, S-a > 0, E > 0), so the sign-flip
// reduces to setting the sign bit.
__device__ inline unsigned long long pack_key_pos(float f, unsigned idx) {
    unsigned bits = __float_as_uint(f) | 0x80000000u;
    return ((unsigned long long)bits << 32) | (unsigned)(~idx);
}

// ---------------------------------------------------------------------------
// Init: zero the 256 atomicMax accumulators (bestFg[128] ++ bestBg[128]).
// ---------------------------------------------------------------------------
__global__ void k_init(unsigned long long* __restrict__ best) {
    const int t = threadIdx.x;
    if (t < 2 * NB) best[t] = 0ull;
}

// ---------------------------------------------------------------------------
// Pass 1: sum + IGNORE-fill + FG Gumbel-argmax in one sweep.
// FG key: argmax log(p)+g == argmax (cam+eps)/(-log u); row-sum S cancels.
// Copy-bench style: all loads issued upfront, small per-thread footprint,
// 8 waves/SIMD target (VGPR<=64) so TLP hides HBM latency.
// Plain loads on cam keep it L3-resident for pass 2; nt on noise + out.
// ---------------------------------------------------------------------------
__global__ __launch_bounds__(TPB, 8) void k_fg(const float* __restrict__ cam,
                                               const float* __restrict__ ufg,
                                               int* __restrict__ out,
                                               float* __restrict__ partial,
                                               unsigned long long* __restrict__ bestFg) {
    const int b = blockIdx.y, chunk = blockIdx.x, t = threadIdx.x;
    const long base = (long)b * HW + (long)chunk * EPB;
    const floatx4* c4 = (const floatx4*)(cam + base);
    const floatx4* f4 = (const floatx4*)(ufg + base);
    intx4* o4 = (intx4*)(out + base);
    const intx4 fill = {IGNORE_V, IGNORE_V, IGNORE_V, IGNORE_V};

    floatx4 cv[VPT], uv[VPT];
#pragma unroll
    for (int k = 0; k < VPT; ++k) cv[k] = c4[t + k * TPB];
#pragma unroll
    for (int k = 0; k < VPT; ++k) uv[k] = __builtin_nontemporal_load(&f4[t + k * TPB]);
#pragma unroll
    for (int k = 0; k < VPT; ++k) __builtin_nontemporal_store(fill, &o4[t + k * TPB]);

    float s = 0.f;
    unsigned long long bf = 0ull;
#pragma unroll
    for (int k = 0; k < VPT; ++k) {
        const unsigned idx0 = (unsigned)chunk * (unsigned)EPB + (unsigned)(t + k * TPB) * 4u;
#pragma unroll
        for (int j = 0; j < 4; ++j) {
            float a = cv[k][j] + EPS_F;
            s += a;
            float E = -logf(fmaxf(uv[k][j], 1e-12f));   // -log(u) > 0
            unsigned long long kf = pack_key_pos(a / E, idx0 + j);
            bf = kf > bf ? kf : bf;
        }
    }

    // wave64 reductions -> one partial + one atomicMax per block
#pragma unroll
    for (int off = 32; off > 0; off >>= 1) {
        s += __shfl_down(s, off, 64);
        unsigned long long of = __shfl_down(bf, off, 64);
        bf = of > bf ? of : bf;
    }
    __shared__ float ls[TPB / 64];
    __shared__ unsigned long long lf[TPB / 64];
    if ((t & 63) == 0) { ls[t >> 6] = s; lf[t >> 6] = bf; }
    __syncthreads();
    if (t == 0) {
        float tot = 0.f;
#pragma unroll
        for (int w = 0; w < TPB / 64; ++w) {
            tot += ls[w];
            if (lf[w] > bf) bf = lf[w];
        }
        partial[b * BPR + chunk] = tot;
        atomicMax(&bestFg[b], bf);   // device-scope, order-independent
    }
}

// ---------------------------------------------------------------------------
// Pass 2: BG Gumbel-argmax: argmax log1p(-p)+g == argmax (S-(cam+eps))/(-log u).
// S from pass-1 partials (deterministic sequential sum). cam re-read hits L3.
// ---------------------------------------------------------------------------
__global__ __launch_bounds__(TPB, 8) void k_bg(const float* __restrict__ cam,
                                               const float* __restrict__ ubg,
                                               const float* __restrict__ partial,
                                               unsigned long long* __restrict__ bestBg) {
    const int b = blockIdx.y, chunk = blockIdx.x, t = threadIdx.x;
    const long base = (long)b * HW + (long)chunk * EPB;
    const floatx4* c4 = (const floatx4*)(cam + base);
    const floatx4* g4 = (const floatx4*)(ubg + base);

    floatx4 cv[VPT], uv[VPT];
#pragma unroll
    for (int k = 0; k < VPT; ++k) cv[k] = c4[t + k * TPB];
#pragma unroll
    for (int k = 0; k < VPT; ++k) uv[k] = __builtin_nontemporal_load(&g4[t + k * TPB]);

    float S = 0.f;
    for (int i = 0; i < BPR; ++i) S += partial[b * BPR + i];

    unsigned long long bb = 0ull;
#pragma unroll
    for (int k = 0; k < VPT; ++k) {
        const unsigned idx0 = (unsigned)chunk * (unsigned)EPB + (unsigned)(t + k * TPB) * 4u;
#pragma unroll
        for (int j = 0; j < 4; ++j) {
            float num = S - (cv[k][j] + EPS_F);          // > 0
            float E = -logf(fmaxf(uv[k][j], 1e-12f));
            unsigned long long kb = pack_key_pos(num / E, idx0 + j);
            bb = kb > bb ? kb : bb;
        }
    }

#pragma unroll
    for (int off = 32; off > 0; off >>= 1) {
        unsigned long long ob = __shfl_down(bb, off, 64);
        bb = ob > bb ? ob : bb;
    }
    __shared__ unsigned long long lb[TPB / 64];
    if ((t & 63) == 0) lb[t >> 6] = bb;
    __syncthreads();
    if (t == 0) {
#pragma unroll
        for (int w = 1; w < TPB / 64; ++w)
            if (lb[w] > bb) bb = lb[w];
        atomicMax(&bestBg[b], bb);
    }
}

// ---------------------------------------------------------------------------
// Pass 3: write the dilated 3x3 blocks with the overlap rule:
// fg\bg -> 1, bg\fg -> 0, overlap stays IGNORE.
// ---------------------------------------------------------------------------
__global__ void k_fixup(const unsigned long long* __restrict__ bestFg,
                        const unsigned long long* __restrict__ bestBg,
                        int* __restrict__ out) {
    const int b = threadIdx.x;
    if (b >= NB) return;
    const unsigned long long bf = bestFg[b];
    const unsigned long long bb = bestBg[b];
    const unsigned fidx = ~(unsigned)(bf & 0xFFFFFFFFull);
    const unsigned bidx = ~(unsigned)(bb & 0xFFFFFFFFull);
    const int fr = (int)(fidx / WW), fc = (int)(fidx % WW);
    const int br = (int)(bidx / WW), bc = (int)(bidx % WW);
    const long rb = (long)b * HW;

    for (int dr = -1; dr <= 1; ++dr) {
        for (int dc = -1; dc <= 1; ++dc) {
            int r = fr + dr, c = fc + dc;
            if (r >= 0 && r < HH && c >= 0 && c < WW) {
                bool inBg = (r >= br - 1 && r <= br + 1 && c >= bc - 1 && c <= bc + 1);
                if (!inBg) out[rb + (long)r * WW + c] = 1;
            }
            r = br + dr; c = bc + dc;
            if (r >= 0 && r < HH && c >= 0 && c < WW) {
                bool inFg = (r >= fr - 1 && r <= fr + 1 && c >= fc - 1 && c <= fc + 1);
                if (!inFg) out[rb + (long)r * WW + c] = 0;
            }
        }
    }
}

extern "C" void kernel_launch(void* const* d_in, const int* in_sizes, int n_in,
                              void* d_out, int out_size, void* d_ws, size_t ws_size,
                              hipStream_t stream) {
    const float* cam = (const float*)d_in[0];   // x: [128,1,512,512] f32
    const float* ufg = (const float*)d_in[1];   // u_fg: [128, HW] f32
    const float* ubg = (const float*)d_in[2];   // u_bg: [128, HW] f32
    int* out = (int*)d_out;                     // int32 [128,512,512]

    // Workspace layout (34816 bytes <= proven-available 40960):
    //   [0,     32768)  float partial[NB*BPR]       (128*64*4)
    //   [32768, 33792)  ull   bestFg[NB]            (zero-inited by k_init)
    //   [33792, 34816)  ull   bestBg[NB]
    float* partial = (float*)d_ws;
    unsigned long long* best = (unsigned long long*)((char*)d_ws + 32768);
    unsigned long long* bestFg = best;
    unsigned long long* bestBg = best + NB;

    dim3 grid(BPR, NB);
    k_init<<<1, 256, 0, stream>>>(best);
    k_fg<<<grid, TPB, 0, stream>>>(cam, ufg, out, partial, bestFg);
    k_bg<<<grid, TPB, 0, stream>>>(cam, ubg, partial, bestBg);
    k_fixup<<<1, 128, 0, stream>>>(bestFg, bestBg, out);
}